// Round 3
// baseline (786.123 us; speedup 1.0000x reference)
//
#include <hip/hip_runtime.h>
#include <math.h>

#define VOCAB 32000
#define EMB   32
#define HID   16
#define SEQ   128
#define BATCH 32
#define ROWS  (SEQ*BATCH)    // 4096
#define WIH_LD (EMB+HID)     // 48
#define VBLK  2048           // vocab tile per consumer slot (16 tiles over padded 32768)
#define AGENT __HIP_MEMORY_SCOPE_AGENT

// sync[] layout (u32, 64B-strided to avoid false sharing):
//   sync[0]              x_done counter (embed phase)
//   sync[16   + g*16]    hflag[g]  : H rows for seq-group g (4 timesteps) ready
//   sync[528  + g*16]    cnt[g]    : # vblk blocks done with sumexp partials
//   sync[1040 + g*16]    llflag[g] : logl ready for group g

// ---------------------------------------------------------------------------
// ONE persistent kernel. 512 blocks x 256 threads, 2 blocks/CU (co-resident).
//   phase E : all blocks cooperatively compute X = b_ih + W_ih[:, :EMB] @ emb
//   block 0 : serial recurrence, releases hflag[g] every 4 timesteps
//   slot sid = (grp, vblk): wait hflag[grp] -> sumexp partials -> cnt[grp]++
//             16th finisher reduces 64 partials/row -> logl -> llflag[grp]
//             all 16 then recompute logits and stream out (store-BW bound).
// Pipelining: sumexp VALU + out stores overlap the RNN and each other.
// ---------------------------------------------------------------------------
__global__ __launch_bounds__(256, 2) void k_fused(
    const int* __restrict__ tok, const float* __restrict__ h0f,
    const float* __restrict__ emb, const float* __restrict__ Wih,
    const float* __restrict__ bih, const float* __restrict__ Who,
    const float* __restrict__ bho,
    float* __restrict__ X, float* __restrict__ H,
    float* __restrict__ part, float* __restrict__ logl,
    unsigned* __restrict__ sync_, float* __restrict__ out)
{
    __shared__ float sWh[HID][HID];
    __shared__ float hh[2][BATCH][HID];
    __shared__ unsigned srank;
    int t = threadIdx.x, bid = blockIdx.x;

    // ---------------- phase E: embed+input-proj (blocks 0..255 do the work)
    int gtid = bid*256 + t;                      // 131072 threads, 65536 X vals
    if (gtid < ROWS*HID) {
        int row = gtid >> 4, j = gtid & 15;
        int token = tok[row];
        const float4* ep = (const float4*)(emb + (long)token*EMB);
        const float4* wp = (const float4*)(Wih + j*WIH_LD);  // 192B-aligned
        float acc = bih[j];
        #pragma unroll
        for (int q = 0; q < 8; ++q) {
            float4 e = ep[q], wv = wp[q];
            acc = fmaf(wv.x, e.x, acc); acc = fmaf(wv.y, e.y, acc);
            acc = fmaf(wv.z, e.z, acc); acc = fmaf(wv.w, e.w, acc);
        }
        X[gtid] = acc;
    }
    __syncthreads();
    if (t == 0) {
        __threadfence();                          // make X visible device-wide
        __hip_atomic_fetch_add(&sync_[0], 1u, __ATOMIC_ACQ_REL, AGENT);
    }

    // ---------------- consumer identity + W_ho register tile (overlaps spins)
    int sid  = (bid == 0) ? 511 : bid - 1;        // block 0 takes the LAST slot
    int vblk = sid & 15, grp = sid >> 4;          // grp = 4-timestep group
    float w[2][4][HID]; float bb[2][4];
    #pragma unroll
    for (int g = 0; g < 2; ++g) {
        int base = vblk*VBLK + g*1024 + 4*t;      // 4 consecutive vocab rows
        #pragma unroll
        for (int c = 0; c < 4; ++c) {
            int v = base + c;
            if (v < VOCAB) {
                const float4* qp = (const float4*)(Who + (long)v*HID);
                #pragma unroll
                for (int q = 0; q < 4; ++q) {
                    float4 f = qp[q];
                    w[g][c][4*q+0]=f.x; w[g][c][4*q+1]=f.y;
                    w[g][c][4*q+2]=f.z; w[g][c][4*q+3]=f.w;
                }
                bb[g][c] = bho[v];
            } else {
                #pragma unroll
                for (int i = 0; i < HID; ++i) w[g][c][i] = 0.f;
                bb[g][c] = -1e30f;   // exp->0 in sumexp; write path is guarded
            }
        }
    }

    // ---------------- block 0: serial recurrence (releases hflag per group)
    if (bid == 0) {
        if (t < HID*HID)
            sWh[t/HID][t%HID] = Wih[(t/HID)*WIH_LD + EMB + (t%HID)];
        hh[0][t>>4][t&15]        = h0f[t];
        hh[0][16 + (t>>4)][t&15] = h0f[t + 256];
        if (t == 0) {                              // wait all 512 embed adds
            long gcnt = 0;
            while (__hip_atomic_load(&sync_[0], __ATOMIC_RELAXED, AGENT) < 512u) {
                __builtin_amdgcn_s_sleep(2);
                if (++gcnt > (1L<<23)) break;      // pathological fallback
            }
            __threadfence();                       // acquire
        }
        __syncthreads();

        __builtin_amdgcn_s_setprio(1);             // rnn = serial critical path
        int b0 = t >> 4, j = t & 15;
        int cur = 0;
        float x0 = X[t], x1 = X[t + 256];
        for (int s = 0; s < SEQ; ++s) {
            float xn0 = (s+1 < SEQ) ? X[(s+1)*512 + t]       : 0.f;
            float xn1 = (s+1 < SEQ) ? X[(s+1)*512 + t + 256] : 0.f;
            float a0 = x0, a1 = x1;
            #pragma unroll
            for (int k = 0; k < HID; ++k) {
                float wv = sWh[j][k];
                a0 = fmaf(wv, hh[cur][b0][k],      a0);
                a1 = fmaf(wv, hh[cur][b0+16][k],   a1);
            }
            float e0 = __expf(fminf(2.f*a0, 30.f));
            float e1 = __expf(fminf(2.f*a1, 30.f));
            float hn0 = (e0 - 1.f) / (e0 + 1.f);
            float hn1 = (e1 - 1.f) / (e1 + 1.f);
            hh[cur^1][b0][j]    = hn0;
            hh[cur^1][b0+16][j] = hn1;
            H[s*512 + t]       = hn0;              // contiguous 2 KB
            H[s*512 + t + 256] = hn1;
            __syncthreads();                       // drains vmcnt too
            if ((s & 3) == 3 && t == 0) {
                __threadfence();                   // wb L2 -> coherence point
                __hip_atomic_store(&sync_[16 + (s>>2)*16], 1u,
                                   __ATOMIC_RELEASE, AGENT);
            }
            x0 = xn0; x1 = xn1; cur ^= 1;
        }
        __builtin_amdgcn_s_setprio(0);
    }

    // ---------------- wait for this slot's H rows (grp*128 .. grp*128+127)
    if (t == 0) {
        long gcnt = 0;
        while (__hip_atomic_load(&sync_[16 + grp*16], __ATOMIC_RELAXED, AGENT) == 0u) {
            __builtin_amdgcn_s_sleep(2);
            if (++gcnt > (1L<<23)) break;
        }
        __threadfence();                           // acquire: inv stale lines
    }
    __syncthreads();

    // ---------------- sumexp partials (identical math to prior k_sumexp)
    int wid = t >> 6, lane = t & 63;
    for (int r = 0; r < 128; r += 2) {
        int row0 = grp*128 + r;
        float h0[HID], h1[HID];
        const float4* hp0 = (const float4*)(H + row0*HID);
        const float4* hp1 = (const float4*)(H + (row0+1)*HID);
        #pragma unroll
        for (int q = 0; q < 4; ++q) {
            float4 f0 = hp0[q], f1 = hp1[q];
            h0[4*q+0]=f0.x; h0[4*q+1]=f0.y; h0[4*q+2]=f0.z; h0[4*q+3]=f0.w;
            h1[4*q+0]=f1.x; h1[4*q+1]=f1.y; h1[4*q+2]=f1.z; h1[4*q+3]=f1.w;
        }
        float p0 = 0.f, p1 = 0.f;
        #pragma unroll
        for (int g = 0; g < 2; ++g)
        #pragma unroll
        for (int c = 0; c < 4; ++c) {
            float a0 = bb[g][c], a1 = bb[g][c];
            #pragma unroll
            for (int i = 0; i < HID; ++i) {
                a0 = fmaf(w[g][c][i], h0[i], a0);
                a1 = fmaf(w[g][c][i], h1[i], a1);
            }
            p0 += __expf(a0);
            p1 += __expf(a1);
        }
        #pragma unroll
        for (int off = 32; off > 0; off >>= 1) {
            p0 += __shfl_xor(p0, off, 64);
            p1 += __shfl_xor(p1, off, 64);
        }
        if (lane == 0) {
            part[(long)row0*64     + vblk*4 + wid] = p0;
            part[(long)(row0+1)*64 + vblk*4 + wid] = p1;
        }
    }
    __syncthreads();
    if (t == 0) {
        __threadfence();                           // publish partials
        srank = __hip_atomic_fetch_add(&sync_[528 + grp*16], 1u,
                                       __ATOMIC_ACQ_REL, AGENT);
    }
    __syncthreads();

    // ---------------- 16th finisher reduces partials -> logl for the group
    if (srank == 15u) {
        if (t == 0) __threadfence();               // acquire side of cnt RMW
        __syncthreads();
        for (int rr = 0; rr < 32; ++rr) {          // 4 waves x 32 rows
            int row = grp*128 + wid*32 + rr;
            float p = part[(long)row*64 + lane];
            #pragma unroll
            for (int off = 32; off > 0; off >>= 1) p += __shfl_xor(p, off, 64);
            if (lane == 0) logl[row] = logf(p);
        }
        __syncthreads();
        if (t == 0) {
            __threadfence();
            __hip_atomic_store(&sync_[1040 + grp*16], 1u,
                               __ATOMIC_RELEASE, AGENT);
        }
    }
    if (t == 0) {
        long gcnt = 0;
        while (__hip_atomic_load(&sync_[1040 + grp*16], __ATOMIC_RELAXED, AGENT) == 0u) {
            __builtin_amdgcn_s_sleep(2);
            if (++gcnt > (1L<<23)) break;
        }
        __threadfence();
    }
    __syncthreads();

    // ---------------- write phase: out[row][v] = logit - logl[row]
    for (int r = 0; r < 128; ++r) {
        int row = grp*128 + r;
        float h[HID];
        const float4* hp = (const float4*)(H + row*HID);
        #pragma unroll
        for (int q = 0; q < 4; ++q) {
            float4 f = hp[q];
            h[4*q+0]=f.x; h[4*q+1]=f.y; h[4*q+2]=f.z; h[4*q+3]=f.w;
        }
        float ll = logl[row];
        float* orow = out + (long)row*VOCAB;
        #pragma unroll
        for (int g = 0; g < 2; ++g) {
            int base = vblk*VBLK + g*1024 + 4*t;
            float acc[4];
            #pragma unroll
            for (int c = 0; c < 4; ++c) {
                float a = bb[g][c];
                #pragma unroll
                for (int i = 0; i < HID; ++i) a = fmaf(w[g][c][i], h[i], a);
                acc[c] = a - ll;
            }
            if (base < VOCAB) {                    // VOCAB%4==0: whole f4 valid
                float4 o; o.x=acc[0]; o.y=acc[1]; o.z=acc[2]; o.w=acc[3];
                *(float4*)(orow + base) = o;
            }
        }
    }
}

// ---------------------------------------------------------------------------
extern "C" void kernel_launch(void* const* d_in, const int* in_sizes, int n_in,
                              void* d_out, int out_size, void* d_ws, size_t ws_size,
                              hipStream_t stream)
{
    const int*   tok = (const int*)  d_in[0];  // (SEQ, BATCH)
    const float* h0  = (const float*)d_in[1];  // (BATCH, HID)
    const float* emb = (const float*)d_in[2];  // (VOCAB, EMB)
    const float* Wih = (const float*)d_in[3];  // (HID, EMB+HID)
    const float* bih = (const float*)d_in[4];  // (HID,)
    const float* Who = (const float*)d_in[5];  // (VOCAB, HID)
    const float* bho = (const float*)d_in[6];  // (VOCAB,)
    float* out = (float*)d_out;                // (SEQ, BATCH, VOCAB)

    char* ws = (char*)d_ws;
    float*    X    = (float*)(ws);              // 256 KB
    float*    H    = (float*)(ws + 262144);     // 256 KB
    float*    part = (float*)(ws + 524288);     // 1 MB
    float*    logl = (float*)(ws + 1572864);    // 16 KB
    unsigned* sync_ = (unsigned*)(ws + 1589248);// 8 KB flag region

    hipMemsetAsync(sync_, 0, 8192, stream);     // flags/counters start at 0
    k_fused<<<dim3(512), 256, 0, stream>>>(tok, h0, emb, Wih, bih, Who, bho,
                                           X, H, part, logl, sync_, out);
}